// Round 1
// baseline (2392.546 us; speedup 1.0000x reference)
//
#include <hip/hip_runtime.h>
#include <math.h>

// Problem constants (B=2, S=512, H=2048, E=16, I=1408, top_k=4, keep_k=2)
#define NTOK 1024
#define HD   2048
#define NE   16
#define ID   1408
#define CAP  1024      // per-expert token capacity (worst case)
#define TT   32        // token tile

// Workspace layout (4-byte units):
//  [0,16)                     counts[E]
//  [16,33)                    offsets[E+1]
//  [64, 64+E*CAP)             tok_list
//  [64+E*CAP, 64+2*E*CAP)     wt_list
//  [ACT_OFF, ...)             act[2*NTOK][ID]
#define TOK_OFF 64
#define WT_OFF  (TOK_OFF + NE * CAP)
#define ACT_OFF (WT_OFF + NE * CAP)

__global__ void router_kernel(const float* __restrict__ x,
                              const float* __restrict__ gw,
                              int* __restrict__ counts,
                              int* __restrict__ tok_list,
                              float* __restrict__ wt_list) {
    int n = blockIdx.x;
    int lane = threadIdx.x;           // 64 threads = 1 wave
    const float* xr = x + (size_t)n * HD;
    __shared__ float slog[NE];
    for (int e = 0; e < NE; ++e) {
        const float* g = gw + (size_t)e * HD;
        float p = 0.f;
        for (int h = lane; h < HD; h += 64) p = fmaf(xr[h], g[h], p);
        #pragma unroll
        for (int off = 32; off > 0; off >>= 1) p += __shfl_xor(p, off, 64);
        if (lane == 0) slog[e] = p;
    }
    __syncthreads();
    if (lane == 0) {
        int i1 = -1, i2 = -1;
        float m1 = -1e30f, m2 = -1e30f;
        for (int e = 0; e < NE; ++e) {
            float v = slog[e];
            if (v > m1) { m2 = m1; i2 = i1; m1 = v; i1 = e; }
            else if (v > m2) { m2 = v; i2 = e; }
        }
        // effective weights: softmax over the two kept logits
        float w1 = 1.f / (1.f + expf(m2 - m1));
        float w2 = 1.f - w1;
        int s1 = atomicAdd(&counts[i1], 1);
        tok_list[i1 * CAP + s1] = n;
        wt_list[i1 * CAP + s1] = w1;
        int s2 = atomicAdd(&counts[i2], 1);
        tok_list[i2 * CAP + s2] = n;
        wt_list[i2 * CAP + s2] = w2;
    }
}

__global__ void prefix_kernel(const int* __restrict__ counts, int* __restrict__ offsets) {
    if (threadIdx.x == 0 && blockIdx.x == 0) {
        int s = 0;
        for (int e = 0; e < NE; ++e) { offsets[e] = s; s += counts[e]; }
        offsets[NE] = s;
    }
}

// Phase A: for each expert slot, a[i] = silu(x·Wg[:,i]) * (x·Wu[:,i])
// grid: (6 i-tiles of 256, 32 token-tiles, 16 experts), block 256
__global__ __launch_bounds__(256) void gateup_kernel(
    const float* __restrict__ x,
    const float* __restrict__ wg, const float* __restrict__ wu,
    const int* __restrict__ counts, const int* __restrict__ offsets,
    const int* __restrict__ tok_list, float* __restrict__ act) {
    int e = blockIdx.z;
    int cnt = counts[e];
    int t0 = blockIdx.y * TT;
    if (t0 >= cnt) return;
    int tlim = min(TT, cnt - t0);
    int base = offsets[e] + t0;
    int i = blockIdx.x * 256 + threadIdx.x;
    bool vi = (i < ID);

    __shared__ float xs[TT][64];
    __shared__ int stok[TT];
    if (threadIdx.x < TT)
        stok[threadIdx.x] = (threadIdx.x < tlim) ? tok_list[e * CAP + t0 + threadIdx.x] : 0;

    float accg[TT], accu[TT];
    #pragma unroll
    for (int t = 0; t < TT; ++t) { accg[t] = 0.f; accu[t] = 0.f; }

    const float* wge = wg + (size_t)e * HD * ID;
    const float* wue = wu + (size_t)e * HD * ID;

    for (int h0 = 0; h0 < HD; h0 += 64) {
        __syncthreads();
        for (int idx = threadIdx.x; idx < TT * 64; idx += 256) {
            int t = idx >> 6, hh = idx & 63;
            xs[t][hh] = (t < tlim) ? x[(size_t)stok[t] * HD + h0 + hh] : 0.f;
        }
        __syncthreads();
        if (vi) {
            const float* pg = wge + (size_t)h0 * ID + i;
            const float* pu = wue + (size_t)h0 * ID + i;
            for (int hh4 = 0; hh4 < 16; ++hh4) {
                float g0 = pg[0], g1 = pg[ID], g2 = pg[2 * ID], g3 = pg[3 * ID];
                float u0 = pu[0], u1 = pu[ID], u2 = pu[2 * ID], u3 = pu[3 * ID];
                pg += 4 * ID; pu += 4 * ID;
                #pragma unroll
                for (int t = 0; t < TT; ++t) {
                    float4 xv = ((const float4*)xs[t])[hh4];
                    accg[t] = fmaf(xv.x, g0, accg[t]);
                    accg[t] = fmaf(xv.y, g1, accg[t]);
                    accg[t] = fmaf(xv.z, g2, accg[t]);
                    accg[t] = fmaf(xv.w, g3, accg[t]);
                    accu[t] = fmaf(xv.x, u0, accu[t]);
                    accu[t] = fmaf(xv.y, u1, accu[t]);
                    accu[t] = fmaf(xv.z, u2, accu[t]);
                    accu[t] = fmaf(xv.w, u3, accu[t]);
                }
            }
        }
    }
    if (vi) {
        #pragma unroll
        for (int t = 0; t < TT; ++t) {
            if (t < tlim) {
                float g = accg[t];
                float s = g / (1.f + expf(-g));        // silu
                act[(size_t)(base + t) * ID + i] = s * accu[t];
            }
        }
    }
}

// Phase B: out[n,h] += w * (a · Wd[:,h]); 2 h-columns per thread
// grid: (4 h-tiles of 512, 32 token-tiles, 16 experts), block 256
__global__ __launch_bounds__(256) void down_kernel(
    const float* __restrict__ wd,
    const int* __restrict__ counts, const int* __restrict__ offsets,
    const int* __restrict__ tok_list, const float* __restrict__ wt_list,
    const float* __restrict__ act, float* __restrict__ out) {
    int e = blockIdx.z;
    int cnt = counts[e];
    int t0 = blockIdx.y * TT;
    if (t0 >= cnt) return;
    int tlim = min(TT, cnt - t0);
    int base = offsets[e] + t0;
    int h1 = blockIdx.x * 512 + threadIdx.x;   // and h1+256

    __shared__ float as[TT][64];
    __shared__ int stok[TT];
    __shared__ float swt[TT];
    if (threadIdx.x < TT) {
        int ok = threadIdx.x < tlim;
        stok[threadIdx.x] = ok ? tok_list[e * CAP + t0 + threadIdx.x] : 0;
        swt[threadIdx.x]  = ok ? wt_list[e * CAP + t0 + threadIdx.x] : 0.f;
    }

    float acc0[TT], acc1[TT];
    #pragma unroll
    for (int t = 0; t < TT; ++t) { acc0[t] = 0.f; acc1[t] = 0.f; }

    const float* wde = wd + (size_t)e * ID * HD;

    for (int i0 = 0; i0 < ID; i0 += 64) {
        __syncthreads();
        for (int idx = threadIdx.x; idx < TT * 64; idx += 256) {
            int t = idx >> 6, ii = idx & 63;
            as[t][ii] = (t < tlim) ? act[(size_t)(base + t) * ID + i0 + ii] : 0.f;
        }
        __syncthreads();
        const float* pd = wde + (size_t)i0 * HD + h1;
        for (int ii4 = 0; ii4 < 16; ++ii4) {
            float d00 = pd[0],       d01 = pd[HD],       d02 = pd[2 * HD],       d03 = pd[3 * HD];
            float d10 = pd[256],     d11 = pd[HD + 256], d12 = pd[2 * HD + 256], d13 = pd[3 * HD + 256];
            pd += 4 * HD;
            #pragma unroll
            for (int t = 0; t < TT; ++t) {
                float4 av = ((const float4*)as[t])[ii4];
                acc0[t] = fmaf(av.x, d00, acc0[t]);
                acc0[t] = fmaf(av.y, d01, acc0[t]);
                acc0[t] = fmaf(av.z, d02, acc0[t]);
                acc0[t] = fmaf(av.w, d03, acc0[t]);
                acc1[t] = fmaf(av.x, d10, acc1[t]);
                acc1[t] = fmaf(av.y, d11, acc1[t]);
                acc1[t] = fmaf(av.z, d12, acc1[t]);
                acc1[t] = fmaf(av.w, d13, acc1[t]);
            }
        }
    }
    #pragma unroll
    for (int t = 0; t < TT; ++t) {
        if (t < tlim) {
            float w = swt[t];
            float* orow = out + (size_t)stok[t] * HD;
            atomicAdd(&orow[h1], w * acc0[t]);
            atomicAdd(&orow[h1 + 256], w * acc1[t]);
        }
    }
}

extern "C" void kernel_launch(void* const* d_in, const int* in_sizes, int n_in,
                              void* d_out, int out_size, void* d_ws, size_t ws_size,
                              hipStream_t stream) {
    const float* x  = (const float*)d_in[0];
    const float* gw = (const float*)d_in[1];
    const float* wg = (const float*)d_in[2];
    const float* wu = (const float*)d_in[3];
    const float* wd = (const float*)d_in[4];
    // d_in[5]=top_k(4), d_in[6]=keep_k(2) — fixed by problem, hard-coded.

    int*   counts   = (int*)d_ws;
    int*   offsets  = counts + NE;
    int*   tok_list = (int*)d_ws + TOK_OFF;
    float* wt_list  = (float*)d_ws + WT_OFF;
    float* act      = (float*)d_ws + ACT_OFF;
    float* out      = (float*)d_out;

    hipMemsetAsync(counts, 0, NE * sizeof(int), stream);
    hipMemsetAsync(out, 0, (size_t)out_size * sizeof(float), stream);

    router_kernel<<<NTOK, 64, 0, stream>>>(x, gw, counts, tok_list, wt_list);
    prefix_kernel<<<1, 64, 0, stream>>>(counts, offsets);

    dim3 gA((ID + 255) / 256, (NTOK + TT - 1) / TT, NE);   // 6 x 32 x 16
    gateup_kernel<<<gA, 256, 0, stream>>>(x, wg, wu, counts, offsets, tok_list, act);

    dim3 gB(HD / 512, (NTOK + TT - 1) / TT, NE);           // 4 x 32 x 16
    down_kernel<<<gB, 256, 0, stream>>>(wd, counts, offsets, tok_list, wt_list, act, out);
}